// Round 7
// baseline (436.301 us; speedup 1.0000x reference)
//
#include <hip/hip_runtime.h>
#include <hip/hip_bf16.h>

// AGREE fused: member-gather -> attention MLP -> masked softmax -> weighted pool
// -> prediction MLP -> sigmoid. One 64-thread block per row (8192 blocks).
//
// Round 6 was the first source that EXECUTED (rounds 1-5 never built: richer C++
// style silently failed compile -> stale stub was benched). Round 6 output was
// all-NaN: the mask probe recognized no valid members (mask is likely f16 or
// int64 encoded: probed bytes all zero) -> softmax sum=0 -> 0*inf = NaN.
// This round: (1) encoding-free element-WIDTH probe in a setup kernel using the
// known prefix structure of the mask (mask = arange < lens), consensus over 64
// rows, result passed via d_ws; (2) runtime probe for f32-vs-bf16 layout of the
// float tensors, with dual load paths and matching output dtype; (3) sum<=0
// guard so NaN is structurally impossible. Style kept to the known-compiling
// round-6 subset: no file-scope helpers/constants, no unions, no namespaces,
// no HIP API calls in kernel_launch besides the two launches.

__global__ void AGREE_12773232738622_probe(
    const void* member_mask,            // [8192, 50] unknown element width
    const void* user_table,             // [100000, 64] f32 or bf16
    int* ws)                            // ws[0] = mask width (1/2/4/8), ws[1] = isf32
{
    __shared__ int s_val[4][64];
    __shared__ int s_len[4][64];
    const int lane = threadIdx.x;       // 64 lanes, lane = sample row
    const unsigned char* mb = (const unsigned char*)member_mask;

    // For each candidate width W: decode row `lane` as 50 elements of W bytes,
    // element valid = any nonzero byte. Must be a nonempty prefix (1..len true,
    // rest false). Max byte offset probed: 8*(50*63+49)+7 < 26 KB <= smallest
    // possible mask buffer (409600 x 1 B), so no OOB under any true width.
    for (int wi = 0; wi < 4; ++wi) {
        int W = 1 << wi;
        int len = 0, ok = 1, prev = 1;
        for (int m = 0; m < 50; ++m) {
            long off = (long)W * (50L * lane + m);
            int nz = 0;
            for (int t = 0; t < W; ++t) nz = nz | (mb[off + t] != 0);
            if (nz && !prev) ok = 0;    // a gap -> not a prefix -> wrong width
            if (nz) len = len + 1;
            prev = nz;
        }
        if (len == 0) ok = 0;
        s_val[wi][lane] = ok;
        s_len[wi][lane] = len;
    }
    __syncthreads();

    if (lane == 0) {
        // True width: valid on all 64 rows AND largest max length (wrong widths
        // that survive the prefix test read OR-ed pairs -> lengths halved).
        int bestW = 1, bestLen = -1;
        for (int wi = 0; wi < 4; ++wi) {
            int allok = 1, mx = 0;
            for (int r = 0; r < 64; ++r) {
                if (!s_val[wi][r]) allok = 0;
                if (s_len[wi][r] > mx) mx = s_len[wi][r];
            }
            if (allok && mx > bestLen) { bestLen = mx; bestW = (1 << wi); }
        }
        ws[0] = bestW;

        // Float layout probe: bf16 N(0,0.125) data never has |x|>4 in the first
        // 64 halfwords; f32 data read as bf16 makes ~half of them huge/NaN.
        int huge = 0;
        for (int i = 0; i < 64; ++i) {
            float v = __bfloat162float(((const __hip_bfloat16*)user_table)[i]);
            float a = (v < 0.0f) ? -v : v;
            if (!(a < 4.0f)) huge = huge + 1;   // catches NaN too
        }
        ws[1] = (huge >= 8) ? 1 : 0;
    }
}

__global__ void AGREE_12773232738622_kernel(
    const int* member_idx,              // [8192, 50] int32
    const void* member_mask,            // [8192, 50] width in ws[0]
    const int* item_inputs,             // [8192] int32
    const void* user_table,             // [100000, 64]
    const void* item_table,             // [50000, 64]
    const void* att_w1,                 // [128, 16]
    const void* att_b1,                 // [16]
    const void* att_w2,                 // [16, 1]
    const void* att_b2,                 // [1]
    const void* pred_w1,                // [192, 8]
    const void* pred_b1,                // [8]
    const void* pred_w2,                // [8, 1]
    const void* pred_b2,                // [1]
    void* out,                          // [8192] (dtype follows ws[1])
    const int* ws)
{
    __shared__ float s_mem[50][65];     // member embeddings (f32), padded
    __shared__ float s_item[64];
    __shared__ float s_wt[50];          // logits then softmax weights
    __shared__ float s_red[64];
    __shared__ float s_p[64][8];
    __shared__ float s_w1[2048];        // att_w1 staged f32
    __shared__ float s_pw[1536];        // pred_w1 staged f32
    __shared__ float s_misc[64];        // 0-15 ab1, 16-31 aw2, 32-39 pb1, 40-47 pw2, 48 ab2, 49 pb2

    const int b    = blockIdx.x;
    const int lane = threadIdx.x;
    const int mode = ws[0];
    const int isf  = ws[1];

    // stage weights to LDS (convert once)
    for (int i = lane; i < 2048; i += 64)
        s_w1[i] = isf ? ((const float*)att_w1)[i]
                      : __bfloat162float(((const __hip_bfloat16*)att_w1)[i]);
    for (int i = lane; i < 1536; i += 64)
        s_pw[i] = isf ? ((const float*)pred_w1)[i]
                      : __bfloat162float(((const __hip_bfloat16*)pred_w1)[i]);
    if (lane < 16) s_misc[lane] = isf ? ((const float*)att_b1)[lane]
                                      : __bfloat162float(((const __hip_bfloat16*)att_b1)[lane]);
    if (lane < 16) s_misc[16 + lane] = isf ? ((const float*)att_w2)[lane]
                                           : __bfloat162float(((const __hip_bfloat16*)att_w2)[lane]);
    if (lane < 8)  s_misc[32 + lane] = isf ? ((const float*)pred_b1)[lane]
                                           : __bfloat162float(((const __hip_bfloat16*)pred_b1)[lane]);
    if (lane < 8)  s_misc[40 + lane] = isf ? ((const float*)pred_w2)[lane]
                                           : __bfloat162float(((const __hip_bfloat16*)pred_w2)[lane]);
    if (lane == 0) {
        s_misc[48] = isf ? ((const float*)att_b2)[0]
                         : __bfloat162float(((const __hip_bfloat16*)att_b2)[0]);
        s_misc[49] = isf ? ((const float*)pred_b2)[0]
                         : __bfloat162float(((const __hip_bfloat16*)pred_b2)[0]);
    }

    const int item_id = item_inputs[b];
    const float itemv = isf ? ((const float*)item_table)[item_id * 64 + lane]
                            : __bfloat162float(((const __hip_bfloat16*)item_table)[item_id * 64 + lane]);
    s_item[lane] = itemv;

    // gather member embeddings into LDS; lane = embedding dim (coalesced rows)
    for (int m = 0; m < 50; ++m) {
        int id = member_idx[b * 50 + m];
        s_mem[m][lane] = isf ? ((const float*)user_table)[id * 64 + lane]
                             : __bfloat162float(((const __hip_bfloat16*)user_table)[id * 64 + lane]);
    }
    __syncthreads();

    // attention MLP: lane = (q = lane>>4 picks m in group of 4, k = lane&15)
    const int k = lane & 15;
    const int q = lane >> 4;

    // item half of layer 1 is m-invariant: compute once
    float iacc = s_misc[k];   // att_b1[k]
    for (int f = 0; f < 64; ++f) iacc += s_item[f] * s_w1[(64 + f) * 16 + k];

    for (int mb = 0; mb < 13; ++mb) {
        int m = mb * 4 + q;
        float acc = iacc;
        if (m < 50) {
            for (int f = 0; f < 64; ++f) acc += s_mem[m][f] * s_w1[f * 16 + k];
        }
        float c = fmaxf(acc, 0.0f) * s_misc[16 + k];   // relu * att_w2[k]
        s_red[lane] = c;
        __syncthreads();
        if (lane < 4) {
            int m2 = mb * 4 + lane;
            if (m2 < 50) {
                float t = s_misc[48];                   // att_b2
                for (int kk = 0; kk < 16; ++kk) t += s_red[lane * 16 + kk];
                s_wt[m2] = t;
            }
        }
        __syncthreads();
    }

    // masked softmax over members (serial on lane 0; all LDS-resident)
    if (lane == 0) {
        float mx = -3.0e38f;
        for (int m = 0; m < 50; ++m) {
            long e0 = 50L * b + m;
            int valid;
            if (mode == 1)      valid = (((const unsigned char*)member_mask)[e0] != 0);
            else if (mode == 2) valid = (((const unsigned short*)member_mask)[e0] != 0);
            else if (mode == 4) valid = (((const unsigned int*)member_mask)[e0] != 0u);
            else {
                const unsigned int* p = (const unsigned int*)member_mask;
                valid = ((p[2 * e0] | p[2 * e0 + 1]) != 0u);
            }
            if (!valid) s_wt[m] = -3.0e38f;
            if (s_wt[m] > mx) mx = s_wt[m];
        }
        float sum = 0.0f;
        for (int m = 0; m < 50; ++m) {
            float e = (s_wt[m] > -1.0e38f) ? expf(s_wt[m] - mx) : 0.0f;
            s_wt[m] = e;
            sum += e;
        }
        if (sum > 0.0f) {
            float inv = 1.0f / sum;
            for (int m = 0; m < 50; ++m) s_wt[m] = s_wt[m] * inv;
        } else {
            // unreachable if the width probe is right; prevents NaN regardless
            for (int m = 0; m < 50; ++m) s_wt[m] = (m == 0) ? 1.0f : 0.0f;
        }
    }
    __syncthreads();

    // weighted pooling: g[lane] = sum_m wt[m] * mem[m][lane]
    float g = 0.0f;
    for (int m = 0; m < 50; ++m) g += s_wt[m] * s_mem[m][lane];

    // prediction MLP: new = [g*item, g, item] (192 features, 3 per lane)
    const float gi = g * itemv;
    for (int k2 = 0; k2 < 8; ++k2) {
        s_p[lane][k2] = gi    * s_pw[lane * 8 + k2]
                      + g     * s_pw[(64 + lane) * 8 + k2]
                      + itemv * s_pw[(128 + lane) * 8 + k2];
    }
    __syncthreads();
    for (int s = 32; s >= 1; s = s >> 1) {
        if (lane < s) {
            for (int k2 = 0; k2 < 8; ++k2)
                s_p[lane][k2] = s_p[lane][k2] + s_p[lane + s][k2];
        }
        __syncthreads();
    }
    if (lane == 0) {
        float z = s_misc[49];                            // pred_b2
        for (int k2 = 0; k2 < 8; ++k2) {
            float h = s_p[0][k2] + s_misc[32 + k2];      // + pred_b1
            if (h < 0.0f) h = 0.0f;
            z += h * s_misc[40 + k2];                    // * pred_w2
        }
        float y = 1.0f / (1.0f + expf(-z));
        if (isf) ((float*)out)[b] = y;
        else     ((__hip_bfloat16*)out)[b] = __float2bfloat16(y);
    }
}

extern "C" void kernel_launch(void* const* d_in, const int* in_sizes, int n_in,
                              void* d_out, int out_size, void* d_ws, size_t ws_size,
                              hipStream_t stream) {
    (void)in_sizes; (void)n_in; (void)out_size; (void)ws_size;
    AGREE_12773232738622_probe<<<1, 64, 0, stream>>>(
        d_in[1], d_in[3], (int*)d_ws);
    AGREE_12773232738622_kernel<<<8192, 64, 0, stream>>>(
        (const int*)d_in[0],
        d_in[1],
        (const int*)d_in[2],
        d_in[3],
        d_in[4],
        d_in[5],
        d_in[6],
        d_in[7],
        d_in[8],
        d_in[9],
        d_in[10],
        d_in[11],
        d_in[12],
        d_out,
        (const int*)d_ws);
}